// Round 1
// baseline (703.022 us; speedup 1.0000x reference)
//
#include <hip/hip_runtime.h>
#include <hip/hip_bf16.h>

#define F_IN 512
#define HID 16

// ---------------- lin1: h0 = relu(x @ W1^T + b1), rn0 = 1/max(||h0||,1e-12) --------------
// block = 256 threads (4 waves); each wave handles 4 nodes (16 lanes per node).
__global__ __launch_bounds__(256) void lin1_kernel(
    const float* __restrict__ x, const float* __restrict__ w1,
    const float* __restrict__ b1, float* __restrict__ h0,
    float* __restrict__ rn0, int N) {
  __shared__ float sW[16 * F_IN];
  for (int i = threadIdx.x; i < 16 * F_IN / 4; i += 256)
    ((float4*)sW)[i] = ((const float4*)w1)[i];
  __syncthreads();

  int wave = (blockIdx.x * 256 + threadIdx.x) >> 6;
  int lane = threadIdx.x & 63;
  int j = lane & 15;          // feature / column-slice id
  int g = lane >> 4;          // node sub-index within wave
  int node = wave * 4 + g;
  if (node >= N) return;

  const float4* xr = (const float4*)(x + (size_t)node * F_IN);
  float acc[16];
#pragma unroll
  for (int k = 0; k < 16; ++k) acc[k] = 0.f;

#pragma unroll
  for (int t = 0; t < 8; ++t) {
    float4 xv = xr[t * 16 + j];  // 16 lanes cover 256B contiguous
#pragma unroll
    for (int k = 0; k < 16; ++k) {
      float4 wv = *(const float4*)&sW[k * F_IN + t * 64 + j * 4];
      acc[k] = fmaf(xv.x, wv.x, fmaf(xv.y, wv.y, fmaf(xv.z, wv.z, fmaf(xv.w, wv.w, acc[k]))));
    }
  }
  // butterfly-reduce each acc[k] across the 16 lanes of this node-group
#pragma unroll
  for (int s = 1; s < 16; s <<= 1) {
#pragma unroll
    for (int k = 0; k < 16; ++k) acc[k] += __shfl_xor(acc[k], s, 64);
  }
  // lane j keeps output feature j
  float hv = 0.f;
#pragma unroll
  for (int k = 0; k < 16; ++k)
    if (j == k) hv = acc[k];
  hv += b1[j];
  hv = fmaxf(hv, 0.f);

  float ns = hv * hv;
#pragma unroll
  for (int s = 1; s < 16; s <<= 1) ns += __shfl_xor(ns, s, 64);

  h0[(size_t)node * 16 + j] = hv;
  if (j == 0) rn0[node] = 1.f / fmaxf(sqrtf(ns), 1e-12f);
}

// ---------------- CSR build ----------------
__global__ void zero_kernel(int* __restrict__ p, int n) {
  int i = blockIdx.x * blockDim.x + threadIdx.x;
  if (i < n) p[i] = 0;
}

__global__ void hist_kernel(const int* __restrict__ dst, int* __restrict__ deg, int E) {
  int e = blockIdx.x * blockDim.x + threadIdx.x;
  if (e < E) atomicAdd(&deg[dst[e]], 1);
}

__global__ __launch_bounds__(1024) void scan1_kernel(
    const int* __restrict__ deg, int* __restrict__ off, int* __restrict__ bsum, int N) {
  __shared__ int s[1024];
  int t = threadIdx.x;
  int gi = blockIdx.x * 1024 + t;
  int v = (gi < N) ? deg[gi] : 0;
  s[t] = v;
  __syncthreads();
  for (int st = 1; st < 1024; st <<= 1) {
    int a = (t >= st) ? s[t - st] : 0;
    __syncthreads();
    s[t] += a;
    __syncthreads();
  }
  if (gi < N) off[gi] = s[t] - v;  // exclusive
  if (t == 1023) bsum[blockIdx.x] = s[t];
}

__global__ __launch_bounds__(128) void scan2_kernel(
    const int* __restrict__ bsum, int* __restrict__ bbase, int nb) {
  __shared__ int s[128];
  int t = threadIdx.x;
  int v = (t < nb) ? bsum[t] : 0;
  s[t] = v;
  __syncthreads();
  for (int st = 1; st < 128; st <<= 1) {
    int a = (t >= st) ? s[t - st] : 0;
    __syncthreads();
    s[t] += a;
    __syncthreads();
  }
  if (t < nb) bbase[t] = s[t] - v;  // exclusive
}

__global__ __launch_bounds__(1024) void scan3_kernel(
    int* __restrict__ off, const int* __restrict__ bbase, int* __restrict__ cur, int N) {
  int gi = blockIdx.x * 1024 + threadIdx.x;
  if (gi < N) {
    int o = off[gi] + bbase[blockIdx.x];
    off[gi] = o;
    cur[gi] = o;
  }
}

__global__ void scatter_kernel(const int* __restrict__ src, const int* __restrict__ dst,
                               int* __restrict__ cur, int* __restrict__ csr, int E) {
  int e = blockIdx.x * blockDim.x + threadIdx.x;
  if (e < E) {
    int d = dst[e];
    int slot = atomicAdd(&cur[d], 1);
    csr[slot] = src[e];
  }
}

// ---------------- AGNN propagation (one wave per dst node) ----------------
// lane = 16*e + j : e = edge sub-slot (4 edges in flight), j = feature.
// out[d] = (sum_e exp(a_e) * h[src_e]) / (sum_e exp(a_e)),  a_e = beta * (h[s].h[d]) * rn[s] * rn[d]
// Self-loop handled implicitly (contribution exp(beta*|h_d|^2*rn_d^2) * h[d]).
// FUSE=true: apply lin2 + log_softmax in epilogue and write final output.
template <bool FUSE>
__global__ __launch_bounds__(256) void prop_kernel(
    const float* __restrict__ hin, const float* __restrict__ rnin,
    const int* __restrict__ off, const int* __restrict__ deg,
    const int* __restrict__ csr, const float* __restrict__ beta_ptr, float beta_val,
    float* __restrict__ hout, float* __restrict__ rnout,
    const float* __restrict__ w2, const float* __restrict__ b2,
    float* __restrict__ out, int N) {
  int d = (blockIdx.x * 256 + threadIdx.x) >> 6;
  int lane = threadIdx.x & 63;
  int j = lane & 15;
  int e = lane >> 4;
  if (d >= N) return;

  float beta = beta_ptr ? beta_ptr[0] : beta_val;
  float hd = hin[(size_t)d * 16 + j];
  float rnd = rnin[d];

  // self-loop dot: |h_d|^2
  float ss = hd * hd;
#pragma unroll
  for (int s = 1; s < 16; s <<= 1) ss += __shfl_xor(ss, s, 64);

  float den, num;
  if (e == 0) {
    float es = __expf(beta * ss * rnd * rnd);
    den = es;
    num = es * hd;
  } else {
    den = 0.f;
    num = 0.f;
  }

  float brnd = beta * rnd;
  int base = off[d];
  int dg = deg[d];
  for (int i = e; i < dg; i += 4) {
    int s = csr[base + i];
    float hs = hin[(size_t)s * 16 + j];
    float dt = hs * hd;
#pragma unroll
    for (int st = 1; st < 16; st <<= 1) dt += __shfl_xor(dt, st, 64);
    float a = brnd * dt * rnin[s];
    float ex = __expf(a);
    den += ex;
    num = fmaf(ex, hs, num);
  }
  // combine the 4 edge-groups
  num += __shfl_xor(num, 16, 64);
  num += __shfl_xor(num, 32, 64);
  den += __shfl_xor(den, 16, 64);
  den += __shfl_xor(den, 32, 64);
  float o = num / den;

  if (!FUSE) {
    if (e == 0) hout[(size_t)d * 16 + j] = o;
    float ns = o * o;
#pragma unroll
    for (int s = 1; s < 16; s <<= 1) ns += __shfl_xor(ns, s, 64);
    if (lane == 0) rnout[d] = 1.f / fmaxf(sqrtf(ns), 1e-12f);
  } else {
    // lin2: logits[j] = b2[j] + sum_m o[m] * w2[j*16+m]
    float lg = b2[j];
    int gbase = lane & 48;
#pragma unroll
    for (int m = 0; m < 16; ++m) {
      float hm = __shfl(o, gbase + m, 64);
      lg = fmaf(hm, w2[j * 16 + m], lg);
    }
    // log_softmax over the 16 lanes of this node-group
    float mx = lg;
#pragma unroll
    for (int s = 1; s < 16; s <<= 1) mx = fmaxf(mx, __shfl_xor(mx, s, 64));
    float exl = __expf(lg - mx);
    float sme = exl;
#pragma unroll
    for (int s = 1; s < 16; s <<= 1) sme += __shfl_xor(sme, s, 64);
    float res = lg - mx - logf(sme);
    if (e == 0) out[(size_t)d * 16 + j] = res;
  }
}

extern "C" void kernel_launch(void* const* d_in, const int* in_sizes, int n_in,
                              void* d_out, int out_size, void* d_ws, size_t ws_size,
                              hipStream_t stream) {
  const float* x   = (const float*)d_in[0];
  const int*   ei  = (const int*)d_in[1];
  const float* w1  = (const float*)d_in[2];
  const float* b1  = (const float*)d_in[3];
  const float* w2  = (const float*)d_in[4];
  const float* b2  = (const float*)d_in[5];
  const float* beta2 = (const float*)d_in[6];
  float* out = (float*)d_out;

  const int N = in_sizes[0] / F_IN;   // 100000
  const int E = in_sizes[1] / 2;      // 3200000
  const int* src = ei;
  const int* dst = ei + E;

  // workspace carve-up (256B aligned)
  char* ws = (char*)d_ws;
  size_t wo = 0;
  auto take = [&](size_t bytes) -> void* {
    void* p = ws + wo;
    wo = (wo + bytes + 255) & ~(size_t)255;
    return p;
  };
  int*   deg   = (int*)take((size_t)N * 4);
  int*   off   = (int*)take((size_t)N * 4);
  int*   cur   = (int*)take((size_t)N * 4);
  int*   bsum  = (int*)take(4096);
  int*   bbase = (int*)take(4096);
  int*   csr   = (int*)take((size_t)E * 4);
  float* h0    = (float*)take((size_t)N * 16 * 4);
  float* rn0   = (float*)take((size_t)N * 4);
  float* h1    = (float*)take((size_t)N * 16 * 4);
  float* rn1   = (float*)take((size_t)N * 4);

  const int nb = (N + 1023) / 1024;  // 98

  // lin1 (+ row norms)
  lin1_kernel<<<(N + 15) / 16, 256, 0, stream>>>(x, w1, b1, h0, rn0, N);

  // CSR build
  zero_kernel<<<(N + 255) / 256, 256, 0, stream>>>(deg, N);
  hist_kernel<<<(E + 255) / 256, 256, 0, stream>>>(dst, deg, E);
  scan1_kernel<<<nb, 1024, 0, stream>>>(deg, off, bsum, N);
  scan2_kernel<<<1, 128, 0, stream>>>(bsum, bbase, nb);
  scan3_kernel<<<nb, 1024, 0, stream>>>(off, bbase, cur, N);
  scatter_kernel<<<(E + 255) / 256, 256, 0, stream>>>(src, dst, cur, csr, E);

  // prop1 (beta = 1.0), writes h1 + rn1
  prop_kernel<false><<<(N + 3) / 4, 256, 0, stream>>>(
      h0, rn0, off, deg, csr, nullptr, 1.0f, h1, rn1, nullptr, nullptr, nullptr, N);

  // prop2 (beta = beta2[0]) fused with lin2 + log_softmax -> out
  prop_kernel<true><<<(N + 3) / 4, 256, 0, stream>>>(
      h1, rn1, off, deg, csr, beta2, 1.0f, nullptr, nullptr, w2, b2, out, N);
}